// Round 3
// baseline (497.692 us; speedup 1.0000x reference)
//
#include <hip/hip_runtime.h>
#include <cstdint>

#define AS1 __attribute__((address_space(1)))
#define AS3 __attribute__((address_space(3)))

// Problem constants (fixed by setup_inputs)
constexpr int B  = 4;
constexpr int C  = 32;
constexpr int H  = 512;
constexpr int Wd = 960;
constexpr int Ht = H / 4;    // 128
constexpr int Wt = Wd / 4;   // 240
constexpr int HW = H * Wd;

constexpr int BLKX  = 256;        // x-pixels per block
constexpr int XMARG = 56;         // disp <= 48+1+slant(~1.4) -> taps >= x-52
constexpr int SELEM = BLKX + 64;  // 320 staged floats per channel
constexpr int CH2   = 16;         // channels per phase (2 phases)
// LDS = 320*16*4 = 20480 B -> 8 blocks/CU -> 32 waves/CU (100%)

__global__ __launch_bounds__(256, 8) void tile_warping_kernel(
    const float* __restrict__ tp,   // [B,3,Ht,Wt]
    const float* __restrict__ fl,   // [B,C,H,W]
    const float* __restrict__ fr,   // [B,C,H,W]
    float* __restrict__ out)        // [B,48,Ht,Wt]
{
    __shared__ float sm[SELEM * CH2];   // 20480 B

    const int lane = threadIdx.x;
    const int x0 = blockIdx.x * BLKX;
    const int y  = blockIdx.y;
    const int b  = blockIdx.z;
    const int xstart = x0 - XMARG;

    const int x = x0 + lane;
    const bool active = (x < Wd);

    // ---- per-thread disparity math (once; shared across both phases) ----
    // k=1 (disp_d=0) is the anchor; k=0/k=2 are exact integer shifts of xs.
    float w = 0.f, w1 = 0.f;
    int om1 = 0;                 // element index of tap F-1
    bool val0 = false, val1 = false, val2 = false;
    if (active) {
        const int ht = y >> 2, ii = y & 3;
        const int wt = x >> 2, jj = x & 3;
        const int tbase = ((b * 3) * Ht + ht) * Wt + wt;
        const float dv  = tp[tbase];
        const float dxv = tp[tbase + Ht * Wt];
        const float dyv = tp[tbase + 2 * Ht * Wt];
        const float oi = (float)ii - 1.5f;
        const float oj = (float)jj - 1.5f;
        // Reference rounding order for disp_d=0: ((d + 0) + oi*dy) + oj*dx
        float disp = ((dv + 0.0f) + oi * dyv) + oj * dxv;
        float xs = (float)x - disp;          // xs for k=1
        float ff = floorf(xs);
        w  = xs - ff;
        w1 = 1.0f - w;
        int F = (int)ff;                     // no clamp needed: valid => in range;
                                             // invalid lanes masked, reads stay in LDS bounds
        om1 = F - 1 - xstart;                // in [lane+4, lane+60] -> always inside sm
        // xs_0 = xs+1 (disp_d=-1), xs_2 = xs-1 (disp_d=+1)
        val0 = (xs >= -1.0f) && (xs <= 958.0f);
        val1 = (xs >=  0.0f) && (xs <= 959.0f);
        val2 = (xs >=  1.0f) && (xs <= 960.0f);
    }

    float s0 = 0.f, s1 = 0.f, s2 = 0.f;

    for (int phase = 0; phase < 2; ++phase) {
        // ---- async stage of 16 fea_r channel-rows into LDS ----
        const float* frrow = fr + (((size_t)b * C + phase * CH2) * H + y) * Wd;
        #pragma unroll
        for (int chunk = 0; chunk < (SELEM * CH2) / (BLKX * 4); ++chunk) {   // 5
            int e   = chunk * (BLKX * 4) + lane * 4;   // element index in sm
            int ch  = e / SELEM;
            int off = e - ch * SELEM;
            int gx  = min(max(xstart + off, 0), Wd - 4);  // clamped slots never read meaningfully
            const float* gp = frrow + (size_t)ch * HW + gx;
            __builtin_amdgcn_global_load_lds((const AS1 float*)gp,
                                             (AS3 float*)(&sm[e]), 16, 0, 0);
        }
        __syncthreads();

        if (active) {
            const float* flp = fl + (((size_t)b * C + phase * CH2) * H + y) * Wd + x;
            #pragma unroll 4
            for (int cc = 0; cc < CH2; ++cc) {
                float l = flp[(size_t)cc * HW];
                const float* bp = sm + cc * SELEM + om1;
                float t0 = bp[0];   // fr[F-1]
                float t1 = bp[1];   // fr[F]
                float t2 = bp[2];   // fr[F+1]
                float t3 = bp[3];   // fr[F+2]
                // k=0: taps (F+1, F+2); k=1: (F, F+1); k=2: (F-1, F)
                float wv0 = val0 ? (t2 * w1 + t3 * w) : 0.f;
                float wv1 = val1 ? (t1 * w1 + t2 * w) : 0.f;
                float wv2 = val2 ? (t0 * w1 + t1 * w) : 0.f;
                s0 += fabsf(l - wv0);
                s1 += fabsf(l - wv1);
                s2 += fabsf(l - wv2);
            }
        }
        __syncthreads();   // protect sm before next phase's DMA overwrites
    }

    if (active) {
        const int ht = y >> 2, ii = y & 3;
        const int wt = x >> 2, jj = x & 3;
        const int obase = ((b * 48) * Ht + ht) * Wt + wt;
        out[obase + (0 * 16 + ii * 4 + jj) * (Ht * Wt)] = s0;
        out[obase + (1 * 16 + ii * 4 + jj) * (Ht * Wt)] = s1;
        out[obase + (2 * 16 + ii * 4 + jj) * (Ht * Wt)] = s2;
    }
}

extern "C" void kernel_launch(void* const* d_in, const int* in_sizes, int n_in,
                              void* d_out, int out_size, void* d_ws, size_t ws_size,
                              hipStream_t stream) {
    const float* tp = (const float*)d_in[0];
    const float* fl = (const float*)d_in[1];
    const float* fr = (const float*)d_in[2];
    float* out = (float*)d_out;

    dim3 grid((Wd + BLKX - 1) / BLKX, H, B);   // (4, 512, 4)
    tile_warping_kernel<<<grid, 256, 0, stream>>>(tp, fl, fr, out);
}